// Round 1
// baseline (44.740 us; speedup 1.0000x reference)
//
#include <hip/hip_runtime.h>

typedef __attribute__((ext_vector_type(8))) short bf16x8;   // 8 bf16 (4 VGPRs)
typedef __attribute__((ext_vector_type(4))) float f32x4;

__device__ inline unsigned short f2bf(float f) {
  unsigned int u = __builtin_bit_cast(unsigned int, f);
  u += 0x7fffu + ((u >> 16) & 1u);     // round-to-nearest-even
  return (unsigned short)(u >> 16);
}

__device__ inline void gload16(const void* g, void* l) {
  __builtin_amdgcn_global_load_lds(
      (const __attribute__((address_space(1))) void*)g,
      (__attribute__((address_space(3))) void*)l, 16, 0, 0);
}

// One wave per row; D = 256 = 64 lanes * 4 floats.
// Writes bf16 copy of the row + exact fp32 sum-of-squares.
__global__ void cvt_rows(const float* __restrict__ src,
                         unsigned short* __restrict__ dst,
                         float* __restrict__ rowsq, int nrows) {
  const int w = threadIdx.x >> 6, lane = threadIdx.x & 63;
  const int row = blockIdx.x * 4 + w;
  if (row >= nrows) return;
  const float4 v = *reinterpret_cast<const float4*>(&src[(size_t)row * 256 + lane * 4]);
  ushort4 b;
  b.x = f2bf(v.x); b.y = f2bf(v.y); b.z = f2bf(v.z); b.w = f2bf(v.w);
  *reinterpret_cast<ushort4*>(&dst[(size_t)row * 256 + lane * 4]) = b;
  float sq = v.x * v.x + v.y * v.y + v.z * v.z + v.w * v.w;
#pragma unroll
  for (int o = 32; o; o >>= 1) sq += __shfl_xor(sq, o);
  if (lane == 0) rowsq[row] = sq;
}

// out[m][n] = fsq[m] + csq[n] - 2 * sum_d A[m][d]*B[n][d]
// A: M x 256 bf16 row-major, B: N x 256 bf16 row-major (B^T-input GEMM).
// 128x128 tile, BK=64, 4 waves (2x2), 16x16x32 bf16 MFMA, m97 structure.
__global__ __launch_bounds__(256) void dist_gemm(
    const unsigned short* __restrict__ A, const unsigned short* __restrict__ B,
    const float* __restrict__ fsq, const float* __restrict__ csq,
    float* __restrict__ out, int M, int N) {
  __shared__ unsigned short As[128 * 64];
  __shared__ unsigned short Bs[128 * 64];
  const int t = threadIdx.x;
  const int w = t >> 6, lane = t & 63;
  const int wr = w >> 1, wc = w & 1;          // wave -> 64x64 quadrant
  const int rl = lane & 15, kh = lane >> 4;   // fragment lane decomposition
  const int m0 = blockIdx.y * 128, n0 = blockIdx.x * 128;

  f32x4 acc[4][4];
#pragma unroll
  for (int i = 0; i < 4; i++)
#pragma unroll
    for (int j = 0; j < 4; j++) acc[i][j] = (f32x4){0.f, 0.f, 0.f, 0.f};

  const int grow = t >> 3;        // 0..31 : row within 32-row issue chunk
  const int gcol = (t & 7) * 8;   // 0..56 : bf16 col offset

  for (int kt = 0; kt < 256; kt += 64) {
#pragma unroll
    for (int i = 0; i < 4; i++) {
      gload16(&A[(size_t)(m0 + i * 32 + grow) * 256 + kt + gcol],
              (char*)As + i * 4096 + w * 1024);
      gload16(&B[(size_t)(n0 + i * 32 + grow) * 256 + kt + gcol],
              (char*)Bs + i * 4096 + w * 1024);
    }
    __syncthreads();   // compiler drains vmcnt before barrier
#pragma unroll
    for (int kk = 0; kk < 2; ++kk) {
      bf16x8 af[4], bfr[4];
#pragma unroll
      for (int mi = 0; mi < 4; mi++)
        af[mi] = *reinterpret_cast<const bf16x8*>(
            &As[(wr * 64 + mi * 16 + rl) * 64 + kk * 32 + kh * 8]);
#pragma unroll
      for (int ni = 0; ni < 4; ni++)
        bfr[ni] = *reinterpret_cast<const bf16x8*>(
            &Bs[(wc * 64 + ni * 16 + rl) * 64 + kk * 32 + kh * 8]);
#pragma unroll
      for (int mi = 0; mi < 4; mi++)
#pragma unroll
        for (int ni = 0; ni < 4; ni++)
          acc[mi][ni] = __builtin_amdgcn_mfma_f32_16x16x32_bf16(
              af[mi], bfr[ni], acc[mi][ni], 0, 0, 0);
    }
    __syncthreads();
  }

  // Epilogue: C/D layout col = lane&15, row = (lane>>4)*4 + reg  [m89/m91]
#pragma unroll
  for (int mi = 0; mi < 4; mi++) {
    const int rbase = m0 + wr * 64 + mi * 16 + kh * 4;
    float fr[4];
#pragma unroll
    for (int r = 0; r < 4; r++) fr[r] = fsq[rbase + r];
#pragma unroll
    for (int ni = 0; ni < 4; ni++) {
      const int col = n0 + wc * 64 + ni * 16 + rl;
      const float cs = csq[col];
#pragma unroll
      for (int r = 0; r < 4; r++)
        out[(size_t)(rbase + r) * N + col] = fr[r] + cs - 2.0f * acc[mi][ni][r];
    }
  }
}

extern "C" void kernel_launch(void* const* d_in, const int* in_sizes, int n_in,
                              void* d_out, int out_size, void* d_ws, size_t ws_size,
                              hipStream_t stream) {
  const float* F = (const float*)d_in[0];   // (16, 2048, 256) fp32
  const float* C = (const float*)d_in[1];   // (1, 512, 256) fp32
  float* out = (float*)d_out;               // (16, 2048, 512) fp32
  const int D = 256;
  const int M = in_sizes[0] / D;            // 32768
  const int K = in_sizes[1] / D;            // 512

  unsigned short* Abf = (unsigned short*)d_ws;            // M*D bf16
  unsigned short* Bbf = Abf + (size_t)M * D;              // K*D bf16
  float* fsq = (float*)(Bbf + (size_t)K * D);             // M fp32
  float* csq = fsq + M;                                   // K fp32

  hipLaunchKernelGGL(cvt_rows, dim3((K + 3) / 4), dim3(256), 0, stream, C, Bbf, csq, K);
  hipLaunchKernelGGL(cvt_rows, dim3((M + 3) / 4), dim3(256), 0, stream, F, Abf, fsq, M);
  hipLaunchKernelGGL(dist_gemm, dim3(K / 128, M / 128), dim3(256), 0, stream,
                     Abf, Bbf, fsq, csq, out, M, K);
}